// Round 1
// baseline (2719.034 us; speedup 1.0000x reference)
//
#include <hip/hip_runtime.h>

typedef unsigned short u16;
typedef unsigned int u32;

#define BATCH 4
#define CDIM 384
#define IMG 128
#define HW 16384
#define QKVC 1152
#define NHEADS 8
#define CHD 48
#define DD2 96
#define KFIN 768

// ---------- bf16 helpers (manual RNE, no NaN inputs expected) ----------
__device__ __forceinline__ u16 f2bf(float f){
  union { float f; u32 u; } v; v.f = f;
  u32 u = v.u;
  u32 r = (u + 0x7fffu + ((u >> 16) & 1u)) >> 16;
  return (u16)r;
}
__device__ __forceinline__ float bf2f(u16 h){
  union { u32 u; float f; } v; v.u = ((u32)h) << 16;
  return v.f;
}

// ---------- workspace layout (bytes) ----------
#define OFF_QKVX  ((size_t)0)                         // u16 [4][1152][16384]
#define OFF_QKVM  ((size_t)150994944)                 // u16 [4][1152][16384]
#define OFF_T     ((size_t)301989888)                 // f32 [1152][16384]
#define OFF_SSQ   ((size_t)377487360)                 // f32 [2][4][1152]
#define OFF_S     ((size_t)377524224)                 // f32 [2][4][8][48][96]
#define OFF_ATTN  ((size_t)378703872)                 // f32 [2][4][8][48][96]
#define OFF_AFIN  ((size_t)379883520)                 // f32 [4][384][768]
#define OFF_W2    ((size_t)384602112)                 // f32 [384][768]
#define OFF_B2    ((size_t)385781760)                 // f32 [384]

// ---------- K0: W2 = proj_w @ lin_w ; b2 = proj_w @ lin_b ----------
__global__ void __launch_bounds__(256) k_w2(const float* __restrict__ proj,
                                            const float* __restrict__ lin,
                                            const float* __restrict__ linb,
                                            float* __restrict__ W2,
                                            float* __restrict__ b2){
  int idx = blockIdx.x * 256 + threadIdx.x;
  if (idx < CDIM * KFIN){
    int o = idx / KFIN, d = idx % KFIN;
    float acc = 0.f;
    for (int c = 0; c < CDIM; c++)
      acc = fmaf(proj[o * CDIM + c], lin[c * KFIN + d], acc);
    W2[idx] = acc;
  }
  if (idx < CDIM){
    float acc = 0.f;
    for (int c = 0; c < CDIM; c++)
      acc = fmaf(proj[idx * CDIM + c], linb[c], acc);
    b2[idx] = acc;
  }
}

// ---------- K1: fp32 SGEMM  C[M][N] = A[M][K] * B[K][N] (128x128x16, 8x8 micro) ----------
__global__ void __launch_bounds__(256) k_sgemm_tt(const float* __restrict__ A,
                                                  const float* __restrict__ Bm,
                                                  float* __restrict__ Cm,
                                                  int K, int lda, int ldb, int ldc){
  __shared__ float As[16][132];
  __shared__ float Bs[16][128];
  int tid = threadIdx.x;
  int tx = tid & 15, ty = tid >> 4;
  int m0 = blockIdx.y * 128, n0 = blockIdx.x * 128;
  float acc[8][8];
  #pragma unroll
  for (int i = 0; i < 8; i++)
    #pragma unroll
    for (int j = 0; j < 8; j++) acc[i][j] = 0.f;

  for (int k0 = 0; k0 < K; k0 += 16){
    #pragma unroll
    for (int q = 0; q < 2; q++){
      int idx = tid * 2 + q;
      int m = idx >> 2, k4 = idx & 3;
      float4 v = *(const float4*)(A + (size_t)(m0 + m) * lda + k0 + k4 * 4);
      As[k4*4+0][m] = v.x; As[k4*4+1][m] = v.y; As[k4*4+2][m] = v.z; As[k4*4+3][m] = v.w;
    }
    #pragma unroll
    for (int q = 0; q < 2; q++){
      int idx = tid * 2 + q;
      int k = idx >> 5, n4 = idx & 31;
      *(float4*)&Bs[k][n4*4] = *(const float4*)(Bm + (size_t)(k0 + k) * ldb + n0 + n4 * 4);
    }
    __syncthreads();
    #pragma unroll
    for (int kk = 0; kk < 16; kk++){
      float a[8], bv[8];
      *(float4*)&a[0]  = *(const float4*)&As[kk][ty*8];
      *(float4*)&a[4]  = *(const float4*)&As[kk][ty*8+4];
      *(float4*)&bv[0] = *(const float4*)&Bs[kk][tx*8];
      *(float4*)&bv[4] = *(const float4*)&Bs[kk][tx*8+4];
      #pragma unroll
      for (int i = 0; i < 8; i++)
        #pragma unroll
        for (int j = 0; j < 8; j++)
          acc[i][j] = fmaf(a[i], bv[j], acc[i][j]);
    }
    __syncthreads();
  }
  #pragma unroll
  for (int i = 0; i < 8; i++){
    float* cp = Cm + (size_t)(m0 + ty*8 + i) * ldc + n0 + tx*8;
    float4 v0 = make_float4(acc[i][0], acc[i][1], acc[i][2], acc[i][3]);
    float4 v1 = make_float4(acc[i][4], acc[i][5], acc[i][6], acc[i][7]);
    *(float4*)cp = v0; *(float4*)(cp + 4) = v1;
  }
}

// ---------- K2: depthwise 3x3 + bf16 store + per-channel sum-of-squares ----------
__global__ void __launch_bounds__(256) k_dw(const float* __restrict__ T,
                                            const float* __restrict__ dw,
                                            u16* __restrict__ qkv,
                                            float* __restrict__ ssq){
  int ch = blockIdx.x;   // 0..1151
  int rg = blockIdx.y;   // 0..15 -> rows rg*8 .. +7
  __shared__ float tile[1280];   // 10 rows x 128
  __shared__ float red[256];
  int tid = threadIdx.x;
  int r0 = rg * 8;
  for (int i = tid; i < 1280; i += 256){
    int r = r0 - 1 + i / 128;
    int cx = i % 128;
    tile[i] = (r >= 0 && r < IMG) ? T[(size_t)ch * HW + r * IMG + cx] : 0.f;
  }
  __syncthreads();
  float w[9];
  #pragma unroll
  for (int t = 0; t < 9; t++) w[t] = dw[ch * 9 + t];
  float ss = 0.f;
  #pragma unroll
  for (int p = 0; p < 4; p++){
    int px = tid + p * 256;          // 0..1023
    int rr = px >> 7, x = px & 127;
    float a = 0.f;
    #pragma unroll
    for (int dy = 0; dy < 3; dy++)
      #pragma unroll
      for (int dx = 0; dx < 3; dx++){
        int xx = x + dx - 1;
        if (xx >= 0 && xx < IMG)
          a = fmaf(tile[(rr + dy) * IMG + xx], w[dy * 3 + dx], a);
      }
    qkv[(size_t)ch * HW + (r0 + rr) * IMG + x] = f2bf(a);
    ss = fmaf(a, a, ss);
  }
  red[tid] = ss;
  __syncthreads();
  for (int s = 128; s > 0; s >>= 1){
    if (tid < s) red[tid] += red[tid + s];
    __syncthreads();
  }
  if (tid == 0) atomicAdd(&ssq[ch], red[0]);
}

// ---------- K3: raw attention logits S[iq][b][h][c][d] = sum_n q[c,n]*kc[d,n] ----------
__global__ void __launch_bounds__(256) k_logits(const u16* __restrict__ qkvx,
                                                const u16* __restrict__ qkvm,
                                                float* __restrict__ S){
  int nchunk = blockIdx.x;           // 0..7
  int h = blockIdx.y;                // 0..7
  int z = blockIdx.z;                // 0..7 : iq = z/4, b = z%4
  int iq = z >> 2, b = z & 3;
  const u16* qarr = iq ? qkvm : qkvx;
  __shared__ __align__(16) u16 Qs[48][136];
  __shared__ __align__(16) u16 Ks[96][136];
  int tid = threadIdx.x;
  int tc = tid >> 4, td = tid & 15;  // c-group (0..15 -> 3 rows), d-group (0..15 -> 6 rows)
  float acc[3][6];
  #pragma unroll
  for (int i = 0; i < 3; i++)
    #pragma unroll
    for (int j = 0; j < 6; j++) acc[i][j] = 0.f;

  size_t qbase = ((size_t)b * QKVC + h * CHD) * HW;
  size_t kbase = ((size_t)b * QKVC + CDIM + h * CHD) * HW;
  int nstart = nchunk * 2048;
  for (int nt = nstart; nt < nstart + 2048; nt += 128){
    for (int idx = tid; idx < 48 * 16; idx += 256){
      int c = idx >> 4, g = idx & 15;
      uint4 v = *(const uint4*)(qarr + qbase + (size_t)c * HW + nt + g * 8);
      *(uint4*)&Qs[c][g * 8] = v;
    }
    for (int idx = tid; idx < 96 * 16; idx += 256){
      int d = idx >> 4, g = idx & 15;
      const u16* p = (d < CHD ? qkvx : qkvm) + kbase + (size_t)(d % CHD) * HW + nt + g * 8;
      *(uint4*)&Ks[d][g * 8] = *(const uint4*)p;
    }
    __syncthreads();
    for (int nn = 0; nn < 128; nn++){
      float qv[3], kv[6];
      #pragma unroll
      for (int i = 0; i < 3; i++) qv[i] = bf2f(Qs[tc * 3 + i][nn]);
      #pragma unroll
      for (int j = 0; j < 6; j++) kv[j] = bf2f(Ks[td * 6 + j][nn]);
      #pragma unroll
      for (int i = 0; i < 3; i++)
        #pragma unroll
        for (int j = 0; j < 6; j++)
          acc[i][j] = fmaf(qv[i], kv[j], acc[i][j]);
    }
    __syncthreads();
  }
  float* Sp = S + (((size_t)(iq * BATCH + b) * NHEADS + h) * CHD) * DD2;
  #pragma unroll
  for (int i = 0; i < 3; i++)
    #pragma unroll
    for (int j = 0; j < 6; j++)
      atomicAdd(&Sp[(tc * 3 + i) * DD2 + td * 6 + j], acc[i][j]);
}

// ---------- K4a: scale by norms+temperature, softmax over d ----------
__global__ void __launch_bounds__(128) k_softmax(const float* __restrict__ S,
                                                 const float* __restrict__ ssq,
                                                 const float* __restrict__ temp,
                                                 float* __restrict__ attn){
  int row = blockIdx.x;                 // ((iq*4+b)*8+h)*48+c, 3072 rows
  int c = row % CHD;
  int h = (row / CHD) % NHEADS;
  int b = (row / (CHD * NHEADS)) % BATCH;
  int iq = row / (CHD * NHEADS * BATCH);
  int tid = threadIdx.x;
  __shared__ float sh[128];
  const float* Sp = S + (size_t)row * DD2;
  float ssq_q = ssq[(iq * BATCH + b) * QKVC + h * CHD + c];
  float nq = fmaxf(sqrtf(ssq_q), 1e-12f);
  float tmp = temp[h];
  float logit = -1e30f;
  int d = tid;
  if (d < DD2){
    float ssq_k = ssq[((d < CHD ? 0 : 1) * BATCH + b) * QKVC + CDIM + h * CHD + (d % CHD)];
    float nk = fmaxf(sqrtf(ssq_k), 1e-12f);
    logit = Sp[d] * tmp / (nq * nk);
  }
  sh[tid] = logit; __syncthreads();
  for (int s = 64; s > 0; s >>= 1){
    if (tid < s) sh[tid] = fmaxf(sh[tid], sh[tid + s]);
    __syncthreads();
  }
  float mx = sh[0]; __syncthreads();
  float e = (d < DD2) ? expf(logit - mx) : 0.f;
  sh[tid] = e; __syncthreads();
  for (int s = 64; s > 0; s >>= 1){
    if (tid < s) sh[tid] += sh[tid + s];
    __syncthreads();
  }
  float sum = sh[0];
  if (d < DD2) attn[(size_t)row * DD2 + d] = e / sum;
}

// ---------- K4b: Afin[b][o][h*96+e] = sum_c W2[o][h*48+c]*attn1[c][e] + W2[o][384+h*48+c]*attn2[c][e] ----------
__global__ void __launch_bounds__(128) k_mmat(const float* __restrict__ attn,
                                              const float* __restrict__ W2,
                                              float* __restrict__ Afin){
  int oz = blockIdx.x;   // 0..47 (8 o's each)
  int h = blockIdx.y;
  int b = blockIdx.z;
  __shared__ float a1[CHD * DD2];
  __shared__ float a2[CHD * DD2];
  int tid = threadIdx.x;
  const float* A1 = attn + ((size_t)(0 * BATCH + b) * NHEADS + h) * CHD * DD2;
  const float* A2 = attn + ((size_t)(1 * BATCH + b) * NHEADS + h) * CHD * DD2;
  for (int i = tid; i < CHD * DD2; i += 128){ a1[i] = A1[i]; a2[i] = A2[i]; }
  __syncthreads();
  int e = tid;
  if (e < DD2){
    for (int oo = 0; oo < 8; oo++){
      int o = oz * 8 + oo;
      float acc = 0.f;
      #pragma unroll 4
      for (int cc = 0; cc < CHD; cc++){
        acc = fmaf(W2[o * KFIN + h * CHD + cc],        a1[cc * DD2 + e], acc);
        acc = fmaf(W2[o * KFIN + CDIM + h * CHD + cc], a2[cc * DD2 + e], acc);
      }
      Afin[((size_t)b * CDIM + o) * KFIN + h * DD2 + e] = acc;
    }
  }
}

// ---------- K5: out[b][o][n] = sum_dd Afin[b][o][dd] * Vc[dd][n] + b2[o] ----------
__global__ void __launch_bounds__(256) k_final(const float* __restrict__ Afin,
                                               const u16* __restrict__ qkvx,
                                               const u16* __restrict__ qkvm,
                                               const float* __restrict__ b2,
                                               float* __restrict__ outp){
  int b = blockIdx.z;
  int m0 = blockIdx.y * 128, n0 = blockIdx.x * 128;
  const float* A = Afin + (size_t)b * CDIM * KFIN;
  __shared__ float As[16][132];
  __shared__ float Bs[16][128];
  int tid = threadIdx.x;
  int tx = tid & 15, ty = tid >> 4;
  float acc[8][8];
  #pragma unroll
  for (int i = 0; i < 8; i++)
    #pragma unroll
    for (int j = 0; j < 8; j++) acc[i][j] = 0.f;

  for (int k0 = 0; k0 < KFIN; k0 += 16){
    #pragma unroll
    for (int q = 0; q < 2; q++){
      int idx = tid * 2 + q;
      int m = idx >> 2, k4 = idx & 3;
      float4 v = *(const float4*)(A + (size_t)(m0 + m) * KFIN + k0 + k4 * 4);
      As[k4*4+0][m] = v.x; As[k4*4+1][m] = v.y; As[k4*4+2][m] = v.z; As[k4*4+3][m] = v.w;
    }
    #pragma unroll
    for (int q = 0; q < 2; q++){
      int idx = tid * 2 + q;
      int k = idx >> 5, n4 = idx & 31;
      int dd = k0 + k;
      int h = dd / DD2, e = dd % DD2;
      const u16* src = (e < CHD ? qkvx : qkvm)
                     + ((size_t)b * QKVC + 2 * CDIM + h * CHD + (e % CHD)) * HW + n0 + n4 * 4;
      uint2 u = *(const uint2*)src;
      float4 v;
      v.x = bf2f((u16)(u.x & 0xffffu)); v.y = bf2f((u16)(u.x >> 16));
      v.z = bf2f((u16)(u.y & 0xffffu)); v.w = bf2f((u16)(u.y >> 16));
      *(float4*)&Bs[k][n4*4] = v;
    }
    __syncthreads();
    #pragma unroll
    for (int kk = 0; kk < 16; kk++){
      float a[8], bv[8];
      *(float4*)&a[0]  = *(const float4*)&As[kk][ty*8];
      *(float4*)&a[4]  = *(const float4*)&As[kk][ty*8+4];
      *(float4*)&bv[0] = *(const float4*)&Bs[kk][tx*8];
      *(float4*)&bv[4] = *(const float4*)&Bs[kk][tx*8+4];
      #pragma unroll
      for (int i = 0; i < 8; i++)
        #pragma unroll
        for (int j = 0; j < 8; j++)
          acc[i][j] = fmaf(a[i], bv[j], acc[i][j]);
    }
    __syncthreads();
  }
  #pragma unroll
  for (int i = 0; i < 8; i++){
    int row = m0 + ty * 8 + i;
    float bias = b2[row];
    float* cp = outp + ((size_t)b * CDIM + row) * HW + n0 + tx * 8;
    float4 v0 = make_float4(acc[i][0]+bias, acc[i][1]+bias, acc[i][2]+bias, acc[i][3]+bias);
    float4 v1 = make_float4(acc[i][4]+bias, acc[i][5]+bias, acc[i][6]+bias, acc[i][7]+bias);
    *(float4*)cp = v0; *(float4*)(cp + 4) = v1;
  }
}

extern "C" void kernel_launch(void* const* d_in, const int* in_sizes, int n_in,
                              void* d_out, int out_size, void* d_ws, size_t ws_size,
                              hipStream_t stream){
  const float* x      = (const float*)d_in[0];
  const float* msg    = (const float*)d_in[1];
  const float* temp   = (const float*)d_in[2];
  const float* qkv_w  = (const float*)d_in[3];
  const float* dw_w   = (const float*)d_in[4];
  const float* proj_w = (const float*)d_in[5];
  const float* lin_w  = (const float*)d_in[6];
  const float* lin_b  = (const float*)d_in[7];
  float* out = (float*)d_out;

  char* ws = (char*)d_ws;
  u16*   qkvx = (u16*)(ws + OFF_QKVX);
  u16*   qkvm = (u16*)(ws + OFF_QKVM);
  float* T    = (float*)(ws + OFF_T);
  float* ssq  = (float*)(ws + OFF_SSQ);
  float* S    = (float*)(ws + OFF_S);
  float* attn = (float*)(ws + OFF_ATTN);
  float* Afin = (float*)(ws + OFF_AFIN);
  float* W2   = (float*)(ws + OFF_W2);
  float* b2   = (float*)(ws + OFF_B2);

  // zero sumsq + S (contiguous region)
  hipMemsetAsync(ws + OFF_SSQ, 0, (OFF_ATTN - OFF_SSQ), stream);

  k_w2<<<dim3((CDIM * KFIN + 255) / 256), dim3(256), 0, stream>>>(proj_w, lin_w, lin_b, W2, b2);

  for (int inp = 0; inp < 2; inp++){
    const float* src = inp ? msg : x;
    u16* qdst = inp ? qkvm : qkvx;
    for (int bb = 0; bb < BATCH; bb++){
      k_sgemm_tt<<<dim3(HW / 128, QKVC / 128), dim3(256), 0, stream>>>(
          qkv_w, src + (size_t)bb * CDIM * HW, T, CDIM, CDIM, HW, HW);
      k_dw<<<dim3(QKVC, IMG / 8), dim3(256), 0, stream>>>(
          T, dw_w, qdst + (size_t)bb * QKVC * HW, ssq + (size_t)(inp * BATCH + bb) * QKVC);
    }
  }

  k_logits<<<dim3(8, NHEADS, 2 * BATCH), dim3(256), 0, stream>>>(qkvx, qkvm, S);
  k_softmax<<<dim3(2 * BATCH * NHEADS * CHD), dim3(128), 0, stream>>>(S, ssq, temp, attn);
  k_mmat<<<dim3(CDIM / 8, NHEADS, BATCH), dim3(128), 0, stream>>>(attn, W2, Afin);
  k_final<<<dim3(HW / 128, CDIM / 128, BATCH), dim3(256), 0, stream>>>(Afin, qkvx, qkvm, b2, out);
}

// Round 2
// 1439.650 us; speedup vs baseline: 1.8887x; 1.8887x over previous
//
#include <hip/hip_runtime.h>

typedef unsigned short u16;
typedef unsigned int u32;

#define BATCH 4
#define CDIM 384
#define IMG 128
#define HW 16384
#define QKVC 1152
#define NHEADS 8
#define CHD 48
#define DD2 96
#define KFIN 768
#define QSTRIDE ((size_t)75497472)   // element offset qkvx -> qkvm in ws

typedef __attribute__((ext_vector_type(8))) short bf16x8;
typedef __attribute__((ext_vector_type(4))) float f32x4;

// ---------- bf16 helpers (manual RNE) ----------
__device__ __forceinline__ u16 f2bf(float f){
  union { float f; u32 u; } v; v.f = f;
  u32 u = v.u;
  u32 r = (u + 0x7fffu + ((u >> 16) & 1u)) >> 16;
  return (u16)r;
}
__device__ __forceinline__ float bf2f(u16 h){
  union { u32 u; float f; } v; v.u = ((u32)h) << 16;
  return v.f;
}

// ---------- workspace layout (bytes) ----------
#define OFF_QKVX  ((size_t)0)                         // u16 [4][1152][16384]
#define OFF_QKVM  ((size_t)150994944)                 // u16 [4][1152][16384]
#define OFF_T     ((size_t)301989888)                 // f32 [1152][16384]
#define OFF_SSQ   ((size_t)377487360)                 // f32 [2][4][1152]
#define OFF_S     ((size_t)377524224)                 // f32 [2][4][8][48][96]
#define OFF_ATTN  ((size_t)378703872)                 // f32 [2][4][8][48][96]
#define OFF_AFINB ((size_t)379883520)                 // bf16 [4][384][768]
#define OFF_W2    ((size_t)382242816)                 // f32 [384][768]
#define OFF_B2    ((size_t)383422464)                 // f32 [384]
#define OFF_WB    ((size_t)383424000)                 // bf16 [1152][384]

// ---------- K0: W2 = proj_w @ lin_w ; b2 = proj_w @ lin_b ; Wb = bf16(qkv_w) ----------
__global__ void __launch_bounds__(256) k_w2(const float* __restrict__ proj,
                                            const float* __restrict__ lin,
                                            const float* __restrict__ linb,
                                            const float* __restrict__ qkvw,
                                            float* __restrict__ W2,
                                            float* __restrict__ b2,
                                            u16* __restrict__ Wb){
  int idx = blockIdx.x * 256 + threadIdx.x;
  if (idx < CDIM * KFIN){
    int o = idx / KFIN, d = idx % KFIN;
    float acc = 0.f;
    for (int c = 0; c < CDIM; c++)
      acc = fmaf(proj[o * CDIM + c], lin[c * KFIN + d], acc);
    W2[idx] = acc;
  }
  if (idx < CDIM){
    float acc = 0.f;
    for (int c = 0; c < CDIM; c++)
      acc = fmaf(proj[idx * CDIM + c], linb[c], acc);
    b2[idx] = acc;
  }
  if (idx < QKVC * CDIM) Wb[idx] = f2bf(qkvw[idx]);
}

// ---------- vc row mapping: dd in [0,768) -> v row pointer ----------
__device__ __forceinline__ const u16* vc_row(const u16* qbase, int bz, int dd){
  int h = dd / DD2;
  int e = dd - h * DD2;
  const u16* p = qbase + (e < CHD ? (size_t)0 : QSTRIDE);
  int c = (e < CHD) ? e : (e - CHD);
  return p + ((size_t)bz * QKVC + 2 * CDIM + h * CHD + c) * HW;
}

// ---------- K1: bf16 MFMA GEMM  C[M][N] = A[M][K] * B[K][N], N=16384 fixed ----------
// BMODE 0: Bsrc = fp32 rows, row k at Bsrc + k*HW (pointwise conv, x/msg)
// BMODE 1: Bsrc = u16 qkvx base, row dd via vc_row (final projection over Vc)
template<int BMODE>
__global__ void __launch_bounds__(256) k_mfma_gemm(
    const u16* __restrict__ A, const void* __restrict__ Bsrc,
    const float* __restrict__ bias, float* __restrict__ C, int M, int K){
  __shared__ __align__(16) u16 As[128][40];
  __shared__ __align__(16) u16 Bs[128][40];
  int tid = threadIdx.x;
  int m0 = blockIdx.x * 128, n0 = blockIdx.y * 128;
  int bz = blockIdx.z;
  if (BMODE == 1){
    A += (size_t)bz * M * K;
    C += (size_t)bz * (size_t)M * HW;
  }
  int kp = tid & 15, ng = tid >> 4;       // B staging: k-pair, n-group
  int arow = tid >> 1, ah = tid & 1;      // A staging
  int w = tid >> 6, lane = tid & 63;
  int wy = w >> 1, wx = w & 1;
  int lm = lane & 15, q = lane >> 4;

  f32x4 acc[4][4];
  #pragma unroll
  for (int i = 0; i < 4; i++)
    #pragma unroll
    for (int j = 0; j < 4; j++) acc[i][j] = (f32x4){0.f,0.f,0.f,0.f};

  for (int k0 = 0; k0 < K; k0 += 32){
    // ---- stage B (transpose to k-major) ----
    if (BMODE == 0){
      const float* r0 = (const float*)Bsrc + (size_t)(k0 + 2*kp) * HW + n0 + ng*8;
      const float* r1 = r0 + HW;
      float4 x0 = *(const float4*)r0;
      float4 x1 = *(const float4*)(r0 + 4);
      float4 y0 = *(const float4*)r1;
      float4 y1 = *(const float4*)(r1 + 4);
      float e0[8] = {x0.x,x0.y,x0.z,x0.w,x1.x,x1.y,x1.z,x1.w};
      float e1[8] = {y0.x,y0.y,y0.z,y0.w,y1.x,y1.y,y1.z,y1.w};
      #pragma unroll
      for (int j = 0; j < 8; j++){
        u32 pk = (u32)f2bf(e0[j]) | ((u32)f2bf(e1[j]) << 16);
        *(u32*)&Bs[ng*8 + j][2*kp] = pk;
      }
    } else {
      const u16* r0 = vc_row((const u16*)Bsrc, bz, k0 + 2*kp)     + n0 + ng*8;
      const u16* r1 = vc_row((const u16*)Bsrc, bz, k0 + 2*kp + 1) + n0 + ng*8;
      uint4 u0 = *(const uint4*)r0;
      uint4 u1 = *(const uint4*)r1;
      u32 aa[4] = {u0.x, u0.y, u0.z, u0.w};
      u32 bb[4] = {u1.x, u1.y, u1.z, u1.w};
      #pragma unroll
      for (int j = 0; j < 8; j++){
        u32 lo = (aa[j >> 1] >> (16 * (j & 1))) & 0xffffu;
        u32 hi = (bb[j >> 1] >> (16 * (j & 1))) & 0xffffu;
        *(u32*)&Bs[ng*8 + j][2*kp] = lo | (hi << 16);
      }
    }
    // ---- stage A (already k-major) ----
    {
      const u16* ap = A + (size_t)(m0 + arow) * K + k0 + ah*16;
      uint4 a0 = *(const uint4*)ap;
      uint4 a1 = *(const uint4*)(ap + 8);
      *(uint4*)&As[arow][ah*16]     = a0;
      *(uint4*)&As[arow][ah*16 + 8] = a1;
    }
    __syncthreads();
    // ---- fragments + MFMA ----
    bf16x8 af[4], bfr[4];
    #pragma unroll
    for (int i = 0; i < 4; i++)
      af[i] = *(const bf16x8*)&As[wy*64 + i*16 + lm][q*8];
    #pragma unroll
    for (int j = 0; j < 4; j++)
      bfr[j] = *(const bf16x8*)&Bs[wx*64 + j*16 + lm][q*8];
    #pragma unroll
    for (int i = 0; i < 4; i++)
      #pragma unroll
      for (int j = 0; j < 4; j++)
        acc[i][j] = __builtin_amdgcn_mfma_f32_16x16x32_bf16(af[i], bfr[j], acc[i][j], 0, 0, 0);
    __syncthreads();
  }
  // ---- epilogue: C[row][col], col=lane&15, row=quad*4+reg ----
  #pragma unroll
  for (int i = 0; i < 4; i++){
    #pragma unroll
    for (int r = 0; r < 4; r++){
      int row = m0 + wy*64 + i*16 + q*4 + r;
      float bv = bias ? bias[row] : 0.f;
      float* cp = C + (size_t)row * HW + n0 + wx*64 + lm;
      #pragma unroll
      for (int j = 0; j < 4; j++)
        cp[j*16] = acc[i][j][r] + bv;
    }
  }
}

// ---------- K2: depthwise 3x3 + bf16 store + per-channel sum-of-squares ----------
__global__ void __launch_bounds__(256) k_dw(const float* __restrict__ T,
                                            const float* __restrict__ dw,
                                            u16* __restrict__ qkv,
                                            float* __restrict__ ssq){
  int ch = blockIdx.x;
  int rg = blockIdx.y;
  __shared__ float tile[1280];
  __shared__ float red[256];
  int tid = threadIdx.x;
  int r0 = rg * 8;
  for (int i = tid; i < 1280; i += 256){
    int r = r0 - 1 + i / 128;
    int cx = i % 128;
    tile[i] = (r >= 0 && r < IMG) ? T[(size_t)ch * HW + r * IMG + cx] : 0.f;
  }
  __syncthreads();
  float w[9];
  #pragma unroll
  for (int t = 0; t < 9; t++) w[t] = dw[ch * 9 + t];
  float ss = 0.f;
  #pragma unroll
  for (int p = 0; p < 4; p++){
    int px = tid + p * 256;
    int rr = px >> 7, x = px & 127;
    float a = 0.f;
    #pragma unroll
    for (int dy = 0; dy < 3; dy++)
      #pragma unroll
      for (int dx = 0; dx < 3; dx++){
        int xx = x + dx - 1;
        if (xx >= 0 && xx < IMG)
          a = fmaf(tile[(rr + dy) * IMG + xx], w[dy * 3 + dx], a);
      }
    qkv[(size_t)ch * HW + (r0 + rr) * IMG + x] = f2bf(a);
    ss = fmaf(a, a, ss);
  }
  red[tid] = ss;
  __syncthreads();
  for (int s = 128; s > 0; s >>= 1){
    if (tid < s) red[tid] += red[tid + s];
    __syncthreads();
  }
  if (tid == 0) atomicAdd(&ssq[ch], red[0]);
}

// ---------- K3: raw attention logits ----------
__global__ void __launch_bounds__(256) k_logits(const u16* __restrict__ qkvx,
                                                const u16* __restrict__ qkvm,
                                                float* __restrict__ S){
  int nchunk = blockIdx.x;
  int h = blockIdx.y;
  int z = blockIdx.z;
  int iq = z >> 2, b = z & 3;
  const u16* qarr = iq ? qkvm : qkvx;
  __shared__ __align__(16) u16 Qs[48][136];
  __shared__ __align__(16) u16 Ks[96][136];
  int tid = threadIdx.x;
  int tc = tid >> 4, td = tid & 15;
  float acc[3][6];
  #pragma unroll
  for (int i = 0; i < 3; i++)
    #pragma unroll
    for (int j = 0; j < 6; j++) acc[i][j] = 0.f;

  size_t qbase = ((size_t)b * QKVC + h * CHD) * HW;
  size_t kbase = ((size_t)b * QKVC + CDIM + h * CHD) * HW;
  int nstart = nchunk * 2048;
  for (int nt = nstart; nt < nstart + 2048; nt += 128){
    for (int idx = tid; idx < 48 * 16; idx += 256){
      int c = idx >> 4, g = idx & 15;
      uint4 v = *(const uint4*)(qarr + qbase + (size_t)c * HW + nt + g * 8);
      *(uint4*)&Qs[c][g * 8] = v;
    }
    for (int idx = tid; idx < 96 * 16; idx += 256){
      int d = idx >> 4, g = idx & 15;
      const u16* p = (d < CHD ? qkvx : qkvm) + kbase + (size_t)(d % CHD) * HW + nt + g * 8;
      *(uint4*)&Ks[d][g * 8] = *(const uint4*)p;
    }
    __syncthreads();
    for (int nn = 0; nn < 128; nn++){
      float qv[3], kv[6];
      #pragma unroll
      for (int i = 0; i < 3; i++) qv[i] = bf2f(Qs[tc * 3 + i][nn]);
      #pragma unroll
      for (int j = 0; j < 6; j++) kv[j] = bf2f(Ks[td * 6 + j][nn]);
      #pragma unroll
      for (int i = 0; i < 3; i++)
        #pragma unroll
        for (int j = 0; j < 6; j++)
          acc[i][j] = fmaf(qv[i], kv[j], acc[i][j]);
    }
    __syncthreads();
  }
  float* Sp = S + (((size_t)(iq * BATCH + b) * NHEADS + h) * CHD) * DD2;
  #pragma unroll
  for (int i = 0; i < 3; i++)
    #pragma unroll
    for (int j = 0; j < 6; j++)
      atomicAdd(&Sp[(tc * 3 + i) * DD2 + td * 6 + j], acc[i][j]);
}

// ---------- K4a: scale by norms+temperature, softmax over d ----------
__global__ void __launch_bounds__(128) k_softmax(const float* __restrict__ S,
                                                 const float* __restrict__ ssq,
                                                 const float* __restrict__ temp,
                                                 float* __restrict__ attn){
  int row = blockIdx.x;
  int c = row % CHD;
  int h = (row / CHD) % NHEADS;
  int b = (row / (CHD * NHEADS)) % BATCH;
  int iq = row / (CHD * NHEADS * BATCH);
  int tid = threadIdx.x;
  __shared__ float sh[128];
  const float* Sp = S + (size_t)row * DD2;
  float ssq_q = ssq[(iq * BATCH + b) * QKVC + h * CHD + c];
  float nq = fmaxf(sqrtf(ssq_q), 1e-12f);
  float tmp = temp[h];
  float logit = -1e30f;
  int d = tid;
  if (d < DD2){
    float ssq_k = ssq[((d < CHD ? 0 : 1) * BATCH + b) * QKVC + CDIM + h * CHD + (d % CHD)];
    float nk = fmaxf(sqrtf(ssq_k), 1e-12f);
    logit = Sp[d] * tmp / (nq * nk);
  }
  sh[tid] = logit; __syncthreads();
  for (int s = 64; s > 0; s >>= 1){
    if (tid < s) sh[tid] = fmaxf(sh[tid], sh[tid + s]);
    __syncthreads();
  }
  float mx = sh[0]; __syncthreads();
  float e = (d < DD2) ? expf(logit - mx) : 0.f;
  sh[tid] = e; __syncthreads();
  for (int s = 64; s > 0; s >>= 1){
    if (tid < s) sh[tid] += sh[tid + s];
    __syncthreads();
  }
  float sum = sh[0];
  if (d < DD2) attn[(size_t)row * DD2 + d] = e / sum;
}

// ---------- K4b: AfinB (bf16) = W2-folded attention ----------
__global__ void __launch_bounds__(128) k_mmat(const float* __restrict__ attn,
                                              const float* __restrict__ W2,
                                              u16* __restrict__ AfinB){
  int oz = blockIdx.x;
  int h = blockIdx.y;
  int b = blockIdx.z;
  __shared__ float a1[CHD * DD2];
  __shared__ float a2[CHD * DD2];
  int tid = threadIdx.x;
  const float* A1 = attn + ((size_t)(0 * BATCH + b) * NHEADS + h) * CHD * DD2;
  const float* A2 = attn + ((size_t)(1 * BATCH + b) * NHEADS + h) * CHD * DD2;
  for (int i = tid; i < CHD * DD2; i += 128){ a1[i] = A1[i]; a2[i] = A2[i]; }
  __syncthreads();
  int e = tid;
  if (e < DD2){
    for (int oo = 0; oo < 8; oo++){
      int o = oz * 8 + oo;
      float acc = 0.f;
      #pragma unroll 4
      for (int cc = 0; cc < CHD; cc++){
        acc = fmaf(W2[o * KFIN + h * CHD + cc],        a1[cc * DD2 + e], acc);
        acc = fmaf(W2[o * KFIN + CDIM + h * CHD + cc], a2[cc * DD2 + e], acc);
      }
      AfinB[((size_t)b * CDIM + o) * KFIN + h * DD2 + e] = f2bf(acc);
    }
  }
}

extern "C" void kernel_launch(void* const* d_in, const int* in_sizes, int n_in,
                              void* d_out, int out_size, void* d_ws, size_t ws_size,
                              hipStream_t stream){
  const float* x      = (const float*)d_in[0];
  const float* msg    = (const float*)d_in[1];
  const float* temp   = (const float*)d_in[2];
  const float* qkv_w  = (const float*)d_in[3];
  const float* dw_w   = (const float*)d_in[4];
  const float* proj_w = (const float*)d_in[5];
  const float* lin_w  = (const float*)d_in[6];
  const float* lin_b  = (const float*)d_in[7];
  float* out = (float*)d_out;

  char* ws = (char*)d_ws;
  u16*   qkvx  = (u16*)(ws + OFF_QKVX);
  u16*   qkvm  = (u16*)(ws + OFF_QKVM);
  float* T     = (float*)(ws + OFF_T);
  float* ssq   = (float*)(ws + OFF_SSQ);
  float* S     = (float*)(ws + OFF_S);
  float* attn  = (float*)(ws + OFF_ATTN);
  u16*   AfinB = (u16*)(ws + OFF_AFINB);
  float* W2    = (float*)(ws + OFF_W2);
  float* b2    = (float*)(ws + OFF_B2);
  u16*   Wb    = (u16*)(ws + OFF_WB);

  hipMemsetAsync(ws + OFF_SSQ, 0, (OFF_ATTN - OFF_SSQ), stream);

  k_w2<<<dim3((QKVC * CDIM + 255) / 256), dim3(256), 0, stream>>>(
      proj_w, lin_w, lin_b, qkv_w, W2, b2, Wb);

  for (int inp = 0; inp < 2; inp++){
    const float* src = inp ? msg : x;
    u16* qdst = inp ? qkvm : qkvx;
    for (int bb = 0; bb < BATCH; bb++){
      k_mfma_gemm<0><<<dim3(QKVC / 128, HW / 128, 1), dim3(256), 0, stream>>>(
          Wb, src + (size_t)bb * CDIM * HW, nullptr, T, QKVC, CDIM);
      k_dw<<<dim3(QKVC, IMG / 8), dim3(256), 0, stream>>>(
          T, dw_w, qdst + (size_t)bb * QKVC * HW, ssq + (size_t)(inp * BATCH + bb) * QKVC);
    }
  }

  k_logits<<<dim3(8, NHEADS, 2 * BATCH), dim3(256), 0, stream>>>(qkvx, qkvm, S);
  k_softmax<<<dim3(2 * BATCH * NHEADS * CHD), dim3(128), 0, stream>>>(S, ssq, temp, attn);
  k_mmat<<<dim3(CDIM / 8, NHEADS, BATCH), dim3(128), 0, stream>>>(attn, W2, AfinB);
  k_mfma_gemm<1><<<dim3(CDIM / 128, HW / 128, BATCH), dim3(256), 0, stream>>>(
      AfinB, qkvx, b2, out, CDIM, KFIN);
}

// Round 3
// 1159.853 us; speedup vs baseline: 2.3443x; 1.2412x over previous
//
#include <hip/hip_runtime.h>

typedef unsigned short u16;
typedef unsigned int u32;

#define BATCH 4
#define CDIM 384
#define IMG 128
#define HW 16384
#define QKVC 1152
#define NHEADS 8
#define CHD 48
#define DD2 96
#define KFIN 768
#define QSTRIDE ((size_t)75497472)   // element offset qkvx -> qkvm in ws

typedef __attribute__((ext_vector_type(8))) short bf16x8;
typedef __attribute__((ext_vector_type(4))) float f32x4;

// ---------- bf16 helpers (manual RNE) ----------
__device__ __forceinline__ u16 f2bf(float f){
  union { float f; u32 u; } v; v.f = f;
  u32 u = v.u;
  u32 r = (u + 0x7fffu + ((u >> 16) & 1u)) >> 16;
  return (u16)r;
}
__device__ __forceinline__ float bf2f(u16 h){
  union { u32 u; float f; } v; v.u = ((u32)h) << 16;
  return v.f;
}

// ---------- workspace layout (bytes) ----------
#define OFF_QKVX  ((size_t)0)                         // u16 [4][1152][16384]
#define OFF_QKVM  ((size_t)150994944)                 // u16 [4][1152][16384]
#define OFF_T     ((size_t)301989888)                 // u16 [1152][16384]  (bf16 now)
#define OFF_SSQ   ((size_t)339738624)                 // f32 [2][4][1152]
#define OFF_S     ((size_t)339775488)                 // f32 [2][4][8][48][96]
#define OFF_ATTN  ((size_t)340955136)                 // f32 [2][4][8][48][96]
#define OFF_AFINB ((size_t)342134784)                 // bf16 [4][384][768]
#define OFF_W2    ((size_t)344494080)                 // f32 [384][768]
#define OFF_B2    ((size_t)345673728)                 // f32 [384]
#define OFF_WB    ((size_t)345675264)                 // bf16 [1152][384]

// ---------- K0: W2 = proj_w @ lin_w ; b2 = proj_w @ lin_b ; Wb = bf16(qkv_w) ----------
__global__ void __launch_bounds__(256) k_w2(const float* __restrict__ proj,
                                            const float* __restrict__ lin,
                                            const float* __restrict__ linb,
                                            const float* __restrict__ qkvw,
                                            float* __restrict__ W2,
                                            float* __restrict__ b2,
                                            u16* __restrict__ Wb){
  int idx = blockIdx.x * 256 + threadIdx.x;
  if (idx < CDIM * KFIN){
    int o = idx / KFIN, d = idx % KFIN;
    float acc = 0.f;
    for (int c = 0; c < CDIM; c++)
      acc = fmaf(proj[o * CDIM + c], lin[c * KFIN + d], acc);
    W2[idx] = acc;
  }
  if (idx < CDIM){
    float acc = 0.f;
    for (int c = 0; c < CDIM; c++)
      acc = fmaf(proj[idx * CDIM + c], linb[c], acc);
    b2[idx] = acc;
  }
  if (idx < QKVC * CDIM) Wb[idx] = f2bf(qkvw[idx]);
}

// ---------- vc row mapping: dd in [0,768) -> v row pointer ----------
__device__ __forceinline__ const u16* vc_row(const u16* qbase, int bz, int dd){
  int h = dd / DD2;
  int e = dd - h * DD2;
  const u16* p = qbase + (e < CHD ? (size_t)0 : QSTRIDE);
  int c = (e < CHD) ? e : (e - CHD);
  return p + ((size_t)bz * QKVC + 2 * CDIM + h * CHD + c) * HW;
}

// ---------- K1: bf16 MFMA GEMM  C[M][N] = A[M][K] * B[K][N], N=16384 fixed ----------
// BMODE 0: Bsrc = fp32 rows (pointwise conv); BMODE 1: Bsrc = u16 qkvx base, rows via vc_row
// CBF16 1: store bf16 C; else fp32 (+bias)
template<int BMODE, int CBF16>
__global__ void __launch_bounds__(256) k_mfma_gemm(
    const u16* __restrict__ A, const void* __restrict__ Bsrc,
    const float* __restrict__ bias, void* __restrict__ Cv, int M, int K){
  __shared__ __align__(16) u16 As[128][40];
  __shared__ __align__(16) u16 Bs[128][40];
  int tid = threadIdx.x;
  int m0 = blockIdx.x * 128, n0 = blockIdx.y * 128;
  int bz = blockIdx.z;
  size_t cofs = 0;
  if (BMODE == 1){
    A += (size_t)bz * M * K;
    cofs = (size_t)bz * (size_t)M * HW;
  }
  int kp = tid & 15, ng = tid >> 4;       // B staging: k-pair, n-group
  int arow = tid >> 1, ah = tid & 1;      // A staging
  int w = tid >> 6, lane = tid & 63;
  int wy = w >> 1, wx = w & 1;
  int lm = lane & 15, q = lane >> 4;

  f32x4 acc[4][4];
  #pragma unroll
  for (int i = 0; i < 4; i++)
    #pragma unroll
    for (int j = 0; j < 4; j++) acc[i][j] = (f32x4){0.f,0.f,0.f,0.f};

  for (int k0 = 0; k0 < K; k0 += 32){
    // ---- stage B (transpose to k-major) ----
    if (BMODE == 0){
      const float* r0 = (const float*)Bsrc + (size_t)(k0 + 2*kp) * HW + n0 + ng*8;
      const float* r1 = r0 + HW;
      float4 x0 = *(const float4*)r0;
      float4 x1 = *(const float4*)(r0 + 4);
      float4 y0 = *(const float4*)r1;
      float4 y1 = *(const float4*)(r1 + 4);
      float e0[8] = {x0.x,x0.y,x0.z,x0.w,x1.x,x1.y,x1.z,x1.w};
      float e1[8] = {y0.x,y0.y,y0.z,y0.w,y1.x,y1.y,y1.z,y1.w};
      #pragma unroll
      for (int j = 0; j < 8; j++){
        u32 pk = (u32)f2bf(e0[j]) | ((u32)f2bf(e1[j]) << 16);
        *(u32*)&Bs[ng*8 + j][2*kp] = pk;
      }
    } else {
      const u16* r0 = vc_row((const u16*)Bsrc, bz, k0 + 2*kp)     + n0 + ng*8;
      const u16* r1 = vc_row((const u16*)Bsrc, bz, k0 + 2*kp + 1) + n0 + ng*8;
      uint4 u0 = *(const uint4*)r0;
      uint4 u1 = *(const uint4*)r1;
      u32 aa[4] = {u0.x, u0.y, u0.z, u0.w};
      u32 bb[4] = {u1.x, u1.y, u1.z, u1.w};
      #pragma unroll
      for (int j = 0; j < 8; j++){
        u32 lo = (aa[j >> 1] >> (16 * (j & 1))) & 0xffffu;
        u32 hi = (bb[j >> 1] >> (16 * (j & 1))) & 0xffffu;
        *(u32*)&Bs[ng*8 + j][2*kp] = lo | (hi << 16);
      }
    }
    // ---- stage A (already k-major) ----
    {
      const u16* ap = A + (size_t)(m0 + arow) * K + k0 + ah*16;
      uint4 a0 = *(const uint4*)ap;
      uint4 a1 = *(const uint4*)(ap + 8);
      *(uint4*)&As[arow][ah*16]     = a0;
      *(uint4*)&As[arow][ah*16 + 8] = a1;
    }
    __syncthreads();
    // ---- fragments + MFMA ----
    bf16x8 af[4], bfr[4];
    #pragma unroll
    for (int i = 0; i < 4; i++)
      af[i] = *(const bf16x8*)&As[wy*64 + i*16 + lm][q*8];
    #pragma unroll
    for (int j = 0; j < 4; j++)
      bfr[j] = *(const bf16x8*)&Bs[wx*64 + j*16 + lm][q*8];
    #pragma unroll
    for (int i = 0; i < 4; i++)
      #pragma unroll
      for (int j = 0; j < 4; j++)
        acc[i][j] = __builtin_amdgcn_mfma_f32_16x16x32_bf16(af[i], bfr[j], acc[i][j], 0, 0, 0);
    __syncthreads();
  }
  // ---- epilogue: C[row][col], col=lane&15, row=quad*4+reg ----
  #pragma unroll
  for (int i = 0; i < 4; i++){
    #pragma unroll
    for (int r = 0; r < 4; r++){
      int row = m0 + wy*64 + i*16 + q*4 + r;
      if (CBF16){
        u16* cp = (u16*)Cv + (size_t)row * HW + n0 + wx*64 + lm;
        #pragma unroll
        for (int j = 0; j < 4; j++)
          cp[j*16] = f2bf(acc[i][j][r]);
      } else {
        float bv = bias ? bias[row] : 0.f;
        float* cp = (float*)Cv + cofs + (size_t)row * HW + n0 + wx*64 + lm;
        #pragma unroll
        for (int j = 0; j < 4; j++)
          cp[j*16] = acc[i][j][r] + bv;
      }
    }
  }
}

// ---------- K2: depthwise 3x3 (bf16 in) + bf16 store + per-channel sum-of-squares ----------
__global__ void __launch_bounds__(256) k_dw(const u16* __restrict__ T,
                                            const float* __restrict__ dw,
                                            u16* __restrict__ qkv,
                                            float* __restrict__ ssq){
  int ch = blockIdx.x;
  int rg = blockIdx.y;
  __shared__ float tile[1280];
  __shared__ float red[256];
  int tid = threadIdx.x;
  int r0 = rg * 8;
  for (int i = tid; i < 1280; i += 256){
    int r = r0 - 1 + i / 128;
    int cx = i % 128;
    tile[i] = (r >= 0 && r < IMG) ? bf2f(T[(size_t)ch * HW + r * IMG + cx]) : 0.f;
  }
  __syncthreads();
  float w[9];
  #pragma unroll
  for (int t = 0; t < 9; t++) w[t] = dw[ch * 9 + t];
  float ss = 0.f;
  #pragma unroll
  for (int p = 0; p < 4; p++){
    int px = tid + p * 256;
    int rr = px >> 7, x = px & 127;
    float a = 0.f;
    #pragma unroll
    for (int dy = 0; dy < 3; dy++)
      #pragma unroll
      for (int dx = 0; dx < 3; dx++){
        int xx = x + dx - 1;
        if (xx >= 0 && xx < IMG)
          a = fmaf(tile[(rr + dy) * IMG + xx], w[dy * 3 + dx], a);
      }
    qkv[(size_t)ch * HW + (r0 + rr) * IMG + x] = f2bf(a);
    ss = fmaf(a, a, ss);
  }
  red[tid] = ss;
  __syncthreads();
  for (int s = 128; s > 0; s >>= 1){
    if (tid < s) red[tid] += red[tid + s];
    __syncthreads();
  }
  if (tid == 0) atomicAdd(&ssq[ch], red[0]);
}

// ---------- K3: logits via MFMA, fragments straight from global (both operands k-contiguous) ----------
// S[iq*48+c][d] per (b,h); 96x96 output, K=16384 split into 16 chunks, f32 atomicAdd combine.
#define LCHUNK 1024
__global__ void __launch_bounds__(256) k_logits_mfma(const u16* __restrict__ qkvx,
                                                     const u16* __restrict__ qkvm,
                                                     float* __restrict__ S){
  int nc = blockIdx.x;               // 0..15
  int bh = blockIdx.y;               // 0..31
  int b = bh & 3, h = bh >> 2;
  int tid = threadIdx.x;
  int w = tid >> 6, lane = tid & 63;
  int wy = w >> 1, wx = w & 1;       // wave covers rows wy*48..+48, cols wx*48..+48
  int lm = lane & 15, quad = lane >> 4;

  const u16* ap[3]; const u16* bp[3];
  #pragma unroll
  for (int i = 0; i < 3; i++){
    int g = wy * 48 + i * 16 + lm;         // q-global-row in [0,96)
    int c = (g < 48) ? g : g - 48;
    ap[i] = ((g < 48) ? qkvx : qkvm) + ((size_t)b * QKVC + h * CHD + c) * HW;
    int d = wx * 48 + i * 16 + lm;         // k_c col in [0,96)
    int cc = (d < 48) ? d : d - 48;
    bp[i] = ((d < 48) ? qkvx : qkvm) + ((size_t)b * QKVC + CDIM + h * CHD + cc) * HW;
  }
  f32x4 acc[3][3];
  #pragma unroll
  for (int i = 0; i < 3; i++)
    #pragma unroll
    for (int j = 0; j < 3; j++) acc[i][j] = (f32x4){0.f,0.f,0.f,0.f};

  int nbeg = nc * LCHUNK + quad * 8;
  int nend = nc * LCHUNK + LCHUNK;
  for (int n = nbeg; n < nend; n += 32){
    bf16x8 af[3], bfr[3];
    #pragma unroll
    for (int i = 0; i < 3; i++) af[i]  = *(const bf16x8*)(ap[i] + n);
    #pragma unroll
    for (int j = 0; j < 3; j++) bfr[j] = *(const bf16x8*)(bp[j] + n);
    #pragma unroll
    for (int i = 0; i < 3; i++)
      #pragma unroll
      for (int j = 0; j < 3; j++)
        acc[i][j] = __builtin_amdgcn_mfma_f32_16x16x32_bf16(af[i], bfr[j], acc[i][j], 0, 0, 0);
  }
  #pragma unroll
  for (int i = 0; i < 3; i++){
    #pragma unroll
    for (int r = 0; r < 4; r++){
      int g = wy * 48 + i * 16 + quad * 4 + r;
      int iq = (g >= 48) ? 1 : 0;
      int c = iq ? g - 48 : g;
      float* Sp = S + (((size_t)(iq * BATCH + b) * NHEADS + h) * CHD + c) * DD2;
      #pragma unroll
      for (int j = 0; j < 3; j++)
        atomicAdd(&Sp[wx * 48 + j * 16 + lm], acc[i][j][r]);
    }
  }
}

// ---------- K4a: scale by norms+temperature, softmax over d ----------
__global__ void __launch_bounds__(128) k_softmax(const float* __restrict__ S,
                                                 const float* __restrict__ ssq,
                                                 const float* __restrict__ temp,
                                                 float* __restrict__ attn){
  int row = blockIdx.x;
  int c = row % CHD;
  int h = (row / CHD) % NHEADS;
  int b = (row / (CHD * NHEADS)) % BATCH;
  int iq = row / (CHD * NHEADS * BATCH);
  int tid = threadIdx.x;
  __shared__ float sh[128];
  const float* Sp = S + (size_t)row * DD2;
  float ssq_q = ssq[(iq * BATCH + b) * QKVC + h * CHD + c];
  float nq = fmaxf(sqrtf(ssq_q), 1e-12f);
  float tmp = temp[h];
  float logit = -1e30f;
  int d = tid;
  if (d < DD2){
    float ssq_k = ssq[((d < CHD ? 0 : 1) * BATCH + b) * QKVC + CDIM + h * CHD + (d % CHD)];
    float nk = fmaxf(sqrtf(ssq_k), 1e-12f);
    logit = Sp[d] * tmp / (nq * nk);
  }
  sh[tid] = logit; __syncthreads();
  for (int s = 64; s > 0; s >>= 1){
    if (tid < s) sh[tid] = fmaxf(sh[tid], sh[tid + s]);
    __syncthreads();
  }
  float mx = sh[0]; __syncthreads();
  float e = (d < DD2) ? expf(logit - mx) : 0.f;
  sh[tid] = e; __syncthreads();
  for (int s = 64; s > 0; s >>= 1){
    if (tid < s) sh[tid] += sh[tid + s];
    __syncthreads();
  }
  float sum = sh[0];
  if (d < DD2) attn[(size_t)row * DD2 + d] = e / sum;
}

// ---------- K4b: AfinB (bf16) = W2-folded attention ----------
__global__ void __launch_bounds__(128) k_mmat(const float* __restrict__ attn,
                                              const float* __restrict__ W2,
                                              u16* __restrict__ AfinB){
  int oz = blockIdx.x;
  int h = blockIdx.y;
  int b = blockIdx.z;
  __shared__ float a1[CHD * DD2];
  __shared__ float a2[CHD * DD2];
  int tid = threadIdx.x;
  const float* A1 = attn + ((size_t)(0 * BATCH + b) * NHEADS + h) * CHD * DD2;
  const float* A2 = attn + ((size_t)(1 * BATCH + b) * NHEADS + h) * CHD * DD2;
  for (int i = tid; i < CHD * DD2; i += 128){ a1[i] = A1[i]; a2[i] = A2[i]; }
  __syncthreads();
  int e = tid;
  if (e < DD2){
    for (int oo = 0; oo < 8; oo++){
      int o = oz * 8 + oo;
      float acc = 0.f;
      #pragma unroll 4
      for (int cc = 0; cc < CHD; cc++){
        acc = fmaf(W2[o * KFIN + h * CHD + cc],        a1[cc * DD2 + e], acc);
        acc = fmaf(W2[o * KFIN + CDIM + h * CHD + cc], a2[cc * DD2 + e], acc);
      }
      AfinB[((size_t)b * CDIM + o) * KFIN + h * DD2 + e] = f2bf(acc);
    }
  }
}

extern "C" void kernel_launch(void* const* d_in, const int* in_sizes, int n_in,
                              void* d_out, int out_size, void* d_ws, size_t ws_size,
                              hipStream_t stream){
  const float* x      = (const float*)d_in[0];
  const float* msg    = (const float*)d_in[1];
  const float* temp   = (const float*)d_in[2];
  const float* qkv_w  = (const float*)d_in[3];
  const float* dw_w   = (const float*)d_in[4];
  const float* proj_w = (const float*)d_in[5];
  const float* lin_w  = (const float*)d_in[6];
  const float* lin_b  = (const float*)d_in[7];
  float* out = (float*)d_out;

  char* ws = (char*)d_ws;
  u16*   qkvx  = (u16*)(ws + OFF_QKVX);
  u16*   qkvm  = (u16*)(ws + OFF_QKVM);
  u16*   T     = (u16*)(ws + OFF_T);
  float* ssq   = (float*)(ws + OFF_SSQ);
  float* S     = (float*)(ws + OFF_S);
  float* attn  = (float*)(ws + OFF_ATTN);
  u16*   AfinB = (u16*)(ws + OFF_AFINB);
  float* W2    = (float*)(ws + OFF_W2);
  float* b2    = (float*)(ws + OFF_B2);
  u16*   Wb    = (u16*)(ws + OFF_WB);

  hipMemsetAsync(ws + OFF_SSQ, 0, (OFF_ATTN - OFF_SSQ), stream);

  k_w2<<<dim3((QKVC * CDIM + 255) / 256), dim3(256), 0, stream>>>(
      proj_w, lin_w, lin_b, qkv_w, W2, b2, Wb);

  for (int inp = 0; inp < 2; inp++){
    const float* src = inp ? msg : x;
    u16* qdst = inp ? qkvm : qkvx;
    for (int bb = 0; bb < BATCH; bb++){
      k_mfma_gemm<0, 1><<<dim3(QKVC / 128, HW / 128, 1), dim3(256), 0, stream>>>(
          Wb, src + (size_t)bb * CDIM * HW, nullptr, T, QKVC, CDIM);
      k_dw<<<dim3(QKVC, IMG / 8), dim3(256), 0, stream>>>(
          T, dw_w, qdst + (size_t)bb * QKVC * HW, ssq + (size_t)(inp * BATCH + bb) * QKVC);
    }
  }

  k_logits_mfma<<<dim3(16, 32), dim3(256), 0, stream>>>(qkvx, qkvm, S);
  k_softmax<<<dim3(2 * BATCH * NHEADS * CHD), dim3(128), 0, stream>>>(S, ssq, temp, attn);
  k_mmat<<<dim3(CDIM / 8, NHEADS, BATCH), dim3(128), 0, stream>>>(attn, W2, AfinB);
  k_mfma_gemm<1, 0><<<dim3(CDIM / 128, HW / 128, BATCH), dim3(256), 0, stream>>>(
      AfinB, qkvx, b2, out, CDIM, KFIN);
}